// Round 4
// baseline (115.839 us; speedup 1.0000x reference)
//
#include <hip/hip_runtime.h>
#include <math.h>

#define WIN 11
#define HALF 5
#define SZ 32
#define PST 33          /* padded LDS row stride */
#define BB 4
#define NG 16
#define NP 64
#define IH 640
#define IW 640
#define CPIX 1024       /* 32*32 per channel */
#define NPIX 3072       /* 3*32*32 per crop */
#define NCROP 320       /* 64 gt + 256 pred */
#define NPAIR 4096      /* 4*16*64 */
#define PAIRGRID 384    /* k_pair blocks; 4 wave-tasks each */
#define SSIM_C1 6.5025f
#define SSIM_C2 58.5225f

// exp(-(i-5)^2/4.5)/sum — 11-tap Gaussian, sigma=1.5, compile-time
#define GW_INIT {0.001028379f, 0.007598757f, 0.036000791f, 0.109360748f, \
                 0.213005174f, 0.266011868f, 0.213005174f, 0.109360748f, \
                 0.036000791f, 0.007598757f, 0.001028379f}

// ---------------- fused: crop-resize + mu/sigma (blocks 0..959)  |  validity list (blocks 960..975) ----------------
__global__ __launch_bounds__(256) void k_crop_valid(const float* __restrict__ imgs,
                                                    const float* __restrict__ gt,
                                                    const float* __restrict__ pr,
                                                    float* __restrict__ crops,
                                                    float* __restrict__ mus,
                                                    float* __restrict__ sigs,
                                                    int* __restrict__ list,
                                                    int* __restrict__ count) {
    const int blk = blockIdx.x;
    const int t = threadIdx.x;

    if (blk >= 3 * NCROP) {
        // ---- validity -> compact list (16 blocks x 256 = 4096 pairs) ----
        int idx = (blk - 3 * NCROP) * 256 + t;
        int b = idx >> 10;
        int r = idx & 1023;
        int gi = r >> 6, pi = r & 63;
        const float* g = gt + (b * NG + gi) * 4;
        const float* p = pr + (b * NP + pi) * 4;
        float gx = g[0], gy = g[1], gw = g[2], gh = g[3];
        float px = p[0], py = p[1], pw = p[2], ph = p[3];
        float tlx = fmaxf(gx - gw * 0.5f, px - pw * 0.5f);
        float tly = fmaxf(gy - gh * 0.5f, py - ph * 0.5f);
        float brx = fminf(gx + gw * 0.5f, px + pw * 0.5f);
        float bry = fminf(gy + gh * 0.5f, py + ph * 0.5f);
        float en = ((tlx < brx) && (tly < bry)) ? 1.f : 0.f;
        float ai = (brx - tlx) * (bry - tly) * en;
        float iou = ai / (gw * gh + pw * ph - ai + 1e-16f);
        if (iou > 0.3f && pw > 2.f && ph > 2.f) {
            int s = atomicAdd(count, 1);   // wave-coalesced (G12)
            list[s] = idx;
        }
        return;
    }

    // ---- crop path: crop-major, channel-minor for image L2 locality ----
    const int crop = blk / 3;
    const int c = blk - crop * 3;
    int b;
    const float* box;
    if (crop < BB * NG) {
        b = crop >> 4;
        box = gt + crop * 4;
    } else {
        int id = crop - BB * NG;
        b = id >> 6;
        box = pr + id * 4;
    }

    __shared__ float s_fx[SZ], s_fy[SZ];
    __shared__ int s_ix0[SZ], s_ix1[SZ], s_iy0[SZ], s_iy1[SZ];
    __shared__ float cr[SZ][PST];
    __shared__ float t1[SZ][PST];
    __shared__ float t2[SZ][PST];

    if (t < SZ) {
        float cx = box[0], cy = box[1], bw = box[2], bh = box[3];
        float x0 = fminf(fmaxf(floorf(cx - bw * 0.5f), 0.f), (float)(IW - 1));
        float x1 = fminf(fmaxf(floorf(cx + bw * 0.5f), 0.f), (float)IW);
        float y0 = fminf(fmaxf(floorf(cy - bh * 0.5f), 0.f), (float)(IH - 1));
        float y1 = fminf(fmaxf(floorf(cy + bh * 0.5f), 0.f), (float)IH);
        float wp = fmaxf(x1 - x0, 1.f);
        float hp = fmaxf(y1 - y0, 1.f);
        float d = (float)t + 0.5f;
        float sx = x0 + fminf(fmaxf(d * wp * (1.f / 32.f) - 0.5f, 0.f), wp - 1.f);
        float flx = floorf(sx);
        s_ix0[t] = (int)flx;
        s_fx[t] = sx - flx;
        s_ix1[t] = min((int)flx + 1, (int)(x0 + wp - 1.f));
        float sy = y0 + fminf(fmaxf(d * hp * (1.f / 32.f) - 0.5f, 0.f), hp - 1.f);
        float fly = floorf(sy);
        s_iy0[t] = (int)fly;
        s_fy[t] = sy - fly;
        s_iy1[t] = min((int)fly + 1, (int)(y0 + hp - 1.f));
    }
    __syncthreads();

    const float* ic = imgs + ((size_t)b * 3 + c) * IH * IW;
    const int y = t >> 3;          // thread owns pixels 4t..4t+3 (same row)
    const int xb = (t & 7) * 4;
    const float fy = s_fy[y];
    const float* r0 = ic + s_iy0[y] * IW;
    const float* r1 = ic + s_iy1[y] * IW;
    float vv[4];
#pragma unroll
    for (int j = 0; j < 4; ++j) {
        int x = xb + j;
        int ix0 = s_ix0[x], ix1 = s_ix1[x];
        float fx = s_fx[x];
        float v00 = r0[ix0], v01 = r0[ix1], v10 = r1[ix0], v11 = r1[ix1];
        float v = v00 * (1.f - fy) * (1.f - fx) + v01 * (1.f - fy) * fx +
                  v10 * fy * (1.f - fx) + v11 * fy * fx;
        vv[j] = v;
        cr[y][x] = v;
    }
    float* dst = crops + (size_t)crop * NPIX + c * CPIX + t * 4;
    *(float4*)dst = make_float4(vv[0], vv[1], vv[2], vv[3]);
    __syncthreads();

    constexpr float GW[WIN] = GW_INIT;
    // horizontal pass on x and x^2
#pragma unroll
    for (int j = 0; j < 4; ++j) {
        int x = xb + j;
        float a1 = 0.f, a2 = 0.f;
#pragma unroll
        for (int k = 0; k < WIN; ++k) {
            int xx = x + k - HALF;
            if (xx >= 0 && xx < SZ) {
                float v = cr[y][xx];
                a1 += GW[k] * v;
                a2 += GW[k] * v * v;
            }
        }
        t1[y][x] = a1;
        t2[y][x] = a2;
    }
    __syncthreads();
    // vertical pass
    float m[4], s[4];
#pragma unroll
    for (int j = 0; j < 4; ++j) {
        int x = xb + j;
        float a1 = 0.f, a2 = 0.f;
#pragma unroll
        for (int k = 0; k < WIN; ++k) {
            int yy = y + k - HALF;
            if (yy >= 0 && yy < SZ) {
                a1 += GW[k] * t1[yy][x];
                a2 += GW[k] * t2[yy][x];
            }
        }
        m[j] = a1;
        s[j] = a2 - a1 * a1;
    }
    float* mdst = mus + (size_t)crop * NPIX + c * CPIX + t * 4;
    float* sdst = sigs + (size_t)crop * NPIX + c * CPIX + t * 4;
    *(float4*)mdst = make_float4(m[0], m[1], m[2], m[3]);
    *(float4*)sdst = make_float4(s[0], s[1], s[2], s[3]);
}

// ---------------- per-(valid-pair, channel): one wave per task, no barriers; fused final reduce ----------------
__global__ __launch_bounds__(256) void k_pair(const int* __restrict__ list,
                                              const int* __restrict__ count,
                                              const float* __restrict__ crops,
                                              const float* __restrict__ mus,
                                              const float* __restrict__ sigs,
                                              float* __restrict__ pairL1,
                                              float* __restrict__ pairSS,
                                              int* __restrict__ done,
                                              float* __restrict__ out) {
    const int n = *count;
    const int ntask = n * 3;                 // task = slot*3 + c
    const int t = threadIdx.x;
    const int wave = t >> 6, lane = t & 63;
    const int y = lane >> 1;                 // 2 lanes per row
    const int xb = (lane & 1) * 16;          // each lane: 16 consecutive px

    __shared__ float gp[4][SZ][PST];         // per-wave slabs — no cross-wave sharing
    __shared__ float tp[4][SZ][PST];
    __shared__ bool s_last;
    float (*GP)[PST] = gp[wave];
    float (*TMP)[PST] = tp[wave];
    constexpr float GW[WIN] = GW_INIT;

    for (int task = blockIdx.x * 4 + wave; task < ntask; task += gridDim.x * 4) {
        const int slot = task / 3;
        const int c = task - slot * 3;
        const int pair = list[slot];
        const int b = pair >> 10;
        const int r = pair & 1023;
        const int gi = r >> 6, pi = r & 63;
        const size_t goff = (size_t)(b * NG + gi) * NPIX + c * CPIX + y * SZ + xb;
        const size_t poff = (size_t)(BB * NG + b * NP + pi) * NPIX + c * CPIX + y * SZ + xb;

        float gv[16], pv[16];
#pragma unroll
        for (int j4 = 0; j4 < 4; ++j4) {
            float4 a = *(const float4*)(crops + goff + j4 * 4);
            float4 bq = *(const float4*)(crops + poff + j4 * 4);
            gv[j4 * 4 + 0] = a.x; gv[j4 * 4 + 1] = a.y; gv[j4 * 4 + 2] = a.z; gv[j4 * 4 + 3] = a.w;
            pv[j4 * 4 + 0] = bq.x; pv[j4 * 4 + 1] = bq.y; pv[j4 * 4 + 2] = bq.z; pv[j4 * 4 + 3] = bq.w;
        }
        float l1 = 0.f;
#pragma unroll
        for (int j = 0; j < 16; ++j) {
            l1 += fabsf(gv[j] - pv[j]);
            GP[y][xb + j] = gv[j] * pv[j];
        }

        // mu/sigma loads issued here; horizontal conv hides their latency
        float m1[16], m2[16], s1[16], s2[16];
#pragma unroll
        for (int j4 = 0; j4 < 4; ++j4) {
            float4 a = *(const float4*)(mus + goff + j4 * 4);
            float4 bq = *(const float4*)(mus + poff + j4 * 4);
            float4 cq = *(const float4*)(sigs + goff + j4 * 4);
            float4 dq = *(const float4*)(sigs + poff + j4 * 4);
            m1[j4 * 4 + 0] = a.x; m1[j4 * 4 + 1] = a.y; m1[j4 * 4 + 2] = a.z; m1[j4 * 4 + 3] = a.w;
            m2[j4 * 4 + 0] = bq.x; m2[j4 * 4 + 1] = bq.y; m2[j4 * 4 + 2] = bq.z; m2[j4 * 4 + 3] = bq.w;
            s1[j4 * 4 + 0] = cq.x; s1[j4 * 4 + 1] = cq.y; s1[j4 * 4 + 2] = cq.z; s1[j4 * 4 + 3] = cq.w;
            s2[j4 * 4 + 0] = dq.x; s2[j4 * 4 + 1] = dq.y; s2[j4 * 4 + 2] = dq.z; s2[j4 * 4 + 3] = dq.w;
        }

        // horizontal conv (intra-wave LDS: ordering via lgkmcnt, no barrier)
#pragma unroll
        for (int j = 0; j < 16; ++j) {
            int x = xb + j;
            float a = 0.f;
#pragma unroll
            for (int k = 0; k < WIN; ++k) {
                int xx = x + k - HALF;
                if (xx >= 0 && xx < SZ) a += GW[k] * GP[y][xx];
            }
            TMP[y][x] = a;
        }

        // vertical conv + SSIM
        float ss = 0.f;
#pragma unroll
        for (int j = 0; j < 16; ++j) {
            int x = xb + j;
            float a = 0.f;
#pragma unroll
            for (int k = 0; k < WIN; ++k) {
                int yy = y + k - HALF;
                if (yy >= 0 && yy < SZ) a += GW[k] * TMP[yy][x];
            }
            float sgp = a - m1[j] * m2[j];
            float num = (2.f * m1[j] * m2[j] + SSIM_C1) * (2.f * sgp + SSIM_C2);
            float den = (m1[j] * m1[j] + m2[j] * m2[j] + SSIM_C1) * (s1[j] + s2[j] + SSIM_C2);
            ss += num / den;
        }

        // 64-lane reduction
#pragma unroll
        for (int off = 32; off > 0; off >>= 1) {
            l1 += __shfl_down(l1, off);
            ss += __shfl_down(ss, off);
        }
        if (lane == 0) {
            pairL1[task] = l1;
            pairSS[task] = ss;
        }
    }

    // ---- last-block final reduce ----
    __threadfence();
    __syncthreads();
    if (t == 0) {
        int d = atomicAdd(done, 1);
        s_last = (d == (int)gridDim.x - 1);
    }
    __syncthreads();
    if (!s_last) return;
    __threadfence();

    float L = 0.f, S = 0.f;
    for (int i = t; i < ntask; i += 256) {
        L += pairL1[i];
        S += pairSS[i];
    }
    __shared__ float rl[4], rs[4];
#pragma unroll
    for (int off = 32; off > 0; off >>= 1) {
        L += __shfl_down(L, off);
        S += __shfl_down(S, off);
    }
    if (lane == 0) { rl[wave] = L; rs[wave] = S; }
    __syncthreads();
    if (t == 0) {
        float cnt = (float)n;
        float Lt = (rl[0] + rl[1] + rl[2] + rl[3]) * (1.0f / (255.0f * (float)NPIX));
        float St = (rs[0] + rs[1] + rs[2] + rs[3]) * (1.0f / (float)NPIX);
        float m = fmaxf(cnt, 1.f);
        float loss = Lt / m + 1.f - St / m;
        out[0] = (cnt > 0.f) ? loss : 0.f;
    }
}

extern "C" void kernel_launch(void* const* d_in, const int* in_sizes, int n_in,
                              void* d_out, int out_size, void* d_ws, size_t ws_size,
                              hipStream_t stream) {
    const float* imgs = (const float*)d_in[0];  // (4,3,640,640)
    const float* gt = (const float*)d_in[1];    // (4,16,4)
    const float* pr = (const float*)d_in[2];    // (4,64,4)

    float* ws = (float*)d_ws;
    float* crops = ws;                                   // 320*3072
    float* mus = crops + (size_t)NCROP * NPIX;
    float* sigs = mus + (size_t)NCROP * NPIX;
    float* pairL1 = sigs + (size_t)NCROP * NPIX;         // 4096*3
    float* pairSS = pairL1 + (size_t)NPAIR * 3;          // 4096*3
    int* list = (int*)(pairSS + (size_t)NPAIR * 3);      // 4096
    int* count = list + NPAIR;                           // 1
    int* done = count + 1;                               // 1

    hipMemsetAsync(count, 0, 2 * sizeof(int), stream);   // count + done
    k_crop_valid<<<3 * NCROP + NPAIR / 256, 256, 0, stream>>>(imgs, gt, pr, crops, mus, sigs,
                                                             list, count);
    k_pair<<<PAIRGRID, 256, 0, stream>>>(list, count, crops, mus, sigs,
                                         pairL1, pairSS, done, (float*)d_out);
}